// Round 7
// baseline (176.754 us; speedup 1.0000x reference)
//
#include <hip/hip_runtime.h>
#include <hip/hip_bf16.h>

typedef __hip_bfloat16 bf16;
typedef __bf16 bfx8 __attribute__((ext_vector_type(8)));
typedef float f32x4 __attribute__((ext_vector_type(4)));

#define Bk   8
#define Ck   384
#define NHk  8
#define Dk   48
#define Dp   64      // padded head dim for MFMA (pads zeroed by padzero_kernel)
#define Nk   1024
#define O3   1152

// ---------------------------------------------------------------------------
// Workspace (bf16 elems):
//   Xt: [b][n][c]        3,145,728   (x transposed, bf16)
//   Wq: [o][c]             442,368   (w_qkv bf16)
//   Wp: [o][c]             147,456   (w_proj bf16)
//   Qp: [b][hd][n][Dp]   4,194,304   (scale folded, d>=48 zeroed)
//   Kp: [b][hd][n][Dp]   4,194,304   (d>=48 zeroed)
//   Vt: [b][hd][d][n]    3,145,728
//   AO: [b][n][c]        3,145,728
// ---------------------------------------------------------------------------

// Prep 0: zero ONLY the d=48..63 pad lanes of Qp/Kp (4 MB instead of a
// 16.8 MB full memset; ws is re-poisoned 0xAA before every launch).
__global__ __launch_bounds__(256) void padzero_kernel(
    bf16* __restrict__ Qp, bf16* __restrict__ Kp)
{
    int idx = blockIdx.x * 256 + threadIdx.x;      // 262144 total
    int buf  = idx >> 17;                          // 0=Q 1=K
    int row  = (idx >> 1) & 65535;                 // b*hd*n rows
    int half = idx & 1;
    bf16* p = (buf ? Kp : Qp) + (size_t)row * Dp + 48 + half * 8;
    *(int4*)p = (int4){0, 0, 0, 0};
}

// Prep 1: transpose+convert x [b][c][n] fp32 -> Xt [b][n][c] bf16.
__global__ __launch_bounds__(256) void xpose_kernel(
    const float* __restrict__ x, bf16* __restrict__ Xt)
{
    __shared__ bf16 tile[32][33];
    const int b = blockIdx.z, c0 = blockIdx.y * 32, n0 = blockIdx.x * 32;
    const int tn = threadIdx.x & 31, tc = threadIdx.x >> 5;
    const float* xb = x + (size_t)b * Ck * Nk;
    #pragma unroll
    for (int i = 0; i < 4; ++i)
        tile[tc + 8 * i][tn] = __float2bfloat16(xb[(size_t)(c0 + tc + 8 * i) * Nk + n0 + tn]);
    __syncthreads();
    bf16* xt = Xt + (size_t)b * Nk * Ck;
    #pragma unroll
    for (int i = 0; i < 4; ++i)
        xt[(size_t)(n0 + tc + 8 * i) * Ck + c0 + tn] = tile[tn][tc + 8 * i];
}

// Prep 2: convert both weight matrices to bf16.
__global__ __launch_bounds__(256) void wconv_kernel(
    const float* __restrict__ wq, const float* __restrict__ wp,
    bf16* __restrict__ Wq, bf16* __restrict__ Wp)
{
    int i = blockIdx.x * 256 + threadIdx.x;
    if (i < O3 * Ck) Wq[i] = __float2bfloat16(wq[i]);
    if (i < Ck * Ck) Wp[i] = __float2bfloat16(wp[i]);
}

// ---------------------------------------------------------------------------
// Kernel 1: QKV GEMM, pure-MFMA, no LDS, 2-deep register pipeline.
// No barriers in the K-loop -> register prefetch actually hides L2 latency
// (unlike the m97 barrier-bound structure).
// ---------------------------------------------------------------------------
__global__ __launch_bounds__(256) void qkv_mfma_kernel(
    const bf16* __restrict__ Xt, const bf16* __restrict__ Wq,
    const float* __restrict__ bias,
    bf16* __restrict__ Qp, bf16* __restrict__ Kp, bf16* __restrict__ Vt)
{
    const int b    = blockIdx.z;
    const int o0   = blockIdx.y * 64;
    const int n0   = blockIdx.x * 128;
    const int wave = threadIdx.x >> 6;
    const int lane = threadIdx.x & 63;
    const int l15  = lane & 15, quad = lane >> 4;
    const int t3   = o0 / Ck;

    const bf16* xr = Xt + ((size_t)b * Nk + n0 + wave * 32 + l15) * Ck + quad * 8;
    const bf16* wr = Wq + (size_t)(o0 + l15) * Ck + quad * 8;

    f32x4 acc[8];
    #pragma unroll
    for (int i = 0; i < 8; ++i) acc[i] = (f32x4){0.f, 0.f, 0.f, 0.f};

    bfx8 fx[3][2], fw[3][4];
    #define LOAD_STEP(s, bf)                                                  \
        {                                                                     \
            _Pragma("unroll")                                                 \
            for (int i = 0; i < 2; ++i)                                       \
                fx[bf][i] = *(const bfx8*)(xr + (size_t)i * 16 * Ck + (s) * 32); \
            _Pragma("unroll")                                                 \
            for (int j = 0; j < 4; ++j)                                       \
                fw[bf][j] = *(const bfx8*)(wr + (size_t)j * 16 * Ck + (s) * 32); \
        }

    LOAD_STEP(0, 0)
    LOAD_STEP(1, 1)

    if (t3 < 2) {
        #pragma unroll
        for (int s = 0; s < 12; ++s) {
            if (s + 2 < 12) LOAD_STEP(s + 2, (s + 2) % 3)
            const int bf = s % 3;
            #pragma unroll
            for (int i = 0; i < 2; ++i)
                #pragma unroll
                for (int j = 0; j < 4; ++j)
                    acc[i * 4 + j] = __builtin_amdgcn_mfma_f32_16x16x32_bf16(
                        fx[bf][i], fw[bf][j], acc[i * 4 + j], 0, 0, 0);
        }
        const float qscale = 0.144337567297406441f;  // 48^-0.5
        #pragma unroll
        for (int j = 0; j < 4; ++j) {
            int o  = o0 + j * 16 + l15;
            float bi = bias[o];
            int r  = o - t3 * Ck;
            int hd = r / Dk, d = r - hd * Dk;
            bf16* dst = (t3 == 0 ? Qp : Kp) + ((size_t)(b * NHk + hd) * Nk) * Dp + d;
            #pragma unroll
            for (int i = 0; i < 2; ++i) {
                #pragma unroll
                for (int reg = 0; reg < 4; ++reg) {
                    int npos = n0 + wave * 32 + i * 16 + quad * 4 + reg;
                    float v = acc[i * 4 + j][reg] + bi;
                    if (t3 == 0) v *= qscale;
                    dst[(size_t)npos * Dp] = __float2bfloat16(v);
                }
            }
        }
    } else {
        #pragma unroll
        for (int s = 0; s < 12; ++s) {
            if (s + 2 < 12) LOAD_STEP(s + 2, (s + 2) % 3)
            const int bf = s % 3;
            #pragma unroll
            for (int j = 0; j < 4; ++j)
                #pragma unroll
                for (int i = 0; i < 2; ++i)
                    acc[j * 2 + i] = __builtin_amdgcn_mfma_f32_16x16x32_bf16(
                        fw[bf][j], fx[bf][i], acc[j * 2 + i], 0, 0, 0);
        }
        #pragma unroll
        for (int j = 0; j < 4; ++j) {
            #pragma unroll
            for (int reg = 0; reg < 4; ++reg) {
                int o  = o0 + j * 16 + quad * 4 + reg;
                float bi = bias[o];
                int r  = o - 2 * Ck;
                int hd = r / Dk, d = r - hd * Dk;
                #pragma unroll
                for (int i = 0; i < 2; ++i) {
                    int npos = n0 + wave * 32 + i * 16 + l15;
                    Vt[((size_t)(b * NHk + hd) * Dk + d) * Nk + npos] =
                        __float2bfloat16(acc[j * 2 + i][reg] + bi);
                }
            }
        }
    }
    #undef LOAD_STEP
}

// ---------------------------------------------------------------------------
// Kernel 2: MFMA attention, no-max softmax, S^T trick (unchanged from R6).
// ---------------------------------------------------------------------------
__global__ __launch_bounds__(256) void attn_kernel(
    const bf16* __restrict__ Qp, const bf16* __restrict__ Kp,
    const bf16* __restrict__ Vt, bf16* __restrict__ AO)
{
    __shared__ __align__(16) short Ks[64 * 72];
    __shared__ __align__(16) short Vs[48 * 72];
    __shared__ __align__(16) short Ps[4 * 32 * 72];
    __shared__ float sums[4][32];

    const int n0   = blockIdx.x * 128;
    const int hd   = blockIdx.y;
    const int b    = blockIdx.z;
    const int t    = threadIdx.x;
    const int wave = t >> 6;
    const int lane = t & 63;
    const int l15  = lane & 15;
    const int quad = lane >> 4;

    const bf16* qb = Qp + (size_t)(b * NHk + hd) * Nk * Dp;
    const bf16* kb = Kp + (size_t)(b * NHk + hd) * Nk * Dp;
    const bf16* vb = Vt + (size_t)(b * NHk + hd) * Dk * Nk;

    bfx8 bq[2][2];
    #pragma unroll
    for (int g = 0; g < 2; ++g) {
        const bf16* qr = qb + (size_t)(n0 + wave * 32 + g * 16 + l15) * Dp;
        bq[g][0] = *(const bfx8*)(qr + quad * 8);
        bq[g][1] = *(const bfx8*)(qr + 32 + quad * 8);
    }

    float l_run[2] = {0.f, 0.f};
    f32x4 oacc[2][3];
    #pragma unroll
    for (int g = 0; g < 2; ++g)
        #pragma unroll
        for (int dc = 0; dc < 3; ++dc) oacc[g][dc] = (f32x4){0.f, 0.f, 0.f, 0.f};

    short* PsW = Ps + wave * 32 * 72;

    for (int k0 = 0; k0 < Nk; k0 += 64) {
        __syncthreads();
        {
            const bf16* src = kb + (size_t)k0 * Dp;
            #pragma unroll
            for (int i = 0; i < 2; ++i) {
                int c = t + 256 * i;
                int row = c >> 3, part = c & 7;
                *(bfx8*)&Ks[row * 72 + part * 8] = *(const bfx8*)(src + c * 8);
            }
            for (int c = t; c < 384; c += 256) {
                int d = c >> 3, part = c & 7;
                *(bfx8*)&Vs[d * 72 + part * 8] =
                    *(const bfx8*)(vb + (size_t)d * Nk + k0 + part * 8);
            }
        }
        __syncthreads();

        f32x4 sf[4][2];
        #pragma unroll
        for (int s = 0; s < 4; ++s) {
            const bfx8 kf0 = *(const bfx8*)&Ks[(s * 16 + l15) * 72 + quad * 8];
            const bfx8 kf1 = *(const bfx8*)&Ks[(s * 16 + l15) * 72 + 32 + quad * 8];
            #pragma unroll
            for (int g = 0; g < 2; ++g) {
                f32x4 z = (f32x4){0.f, 0.f, 0.f, 0.f};
                z = __builtin_amdgcn_mfma_f32_16x16x32_bf16(kf0, bq[g][0], z, 0, 0, 0);
                z = __builtin_amdgcn_mfma_f32_16x16x32_bf16(kf1, bq[g][1], z, 0, 0, 0);
                sf[s][g] = z;
            }
        }

        #pragma unroll
        for (int g = 0; g < 2; ++g) {
            float lsum = 0.f;
            #pragma unroll
            for (int s = 0; s < 4; ++s) {
                ushort4 pk;
                float e0 = __expf(sf[s][g][0]);
                float e1 = __expf(sf[s][g][1]);
                float e2 = __expf(sf[s][g][2]);
                float e3 = __expf(sf[s][g][3]);
                lsum += (e0 + e1) + (e2 + e3);
                bf16 h0 = __float2bfloat16(e0), h1 = __float2bfloat16(e1);
                bf16 h2 = __float2bfloat16(e2), h3 = __float2bfloat16(e3);
                pk.x = *(unsigned short*)&h0; pk.y = *(unsigned short*)&h1;
                pk.z = *(unsigned short*)&h2; pk.w = *(unsigned short*)&h3;
                *(ushort4*)&PsW[(g * 16 + l15) * 72 + s * 16 + quad * 4] = pk;
            }
            l_run[g] += lsum;
        }

        asm volatile("s_waitcnt lgkmcnt(0)" ::: "memory");

        bfx8 ap[2][2];
        #pragma unroll
        for (int g = 0; g < 2; ++g) {
            ap[g][0] = *(const bfx8*)&PsW[(g * 16 + l15) * 72 + quad * 8];
            ap[g][1] = *(const bfx8*)&PsW[(g * 16 + l15) * 72 + 32 + quad * 8];
        }
        #pragma unroll
        for (int dc = 0; dc < 3; ++dc) {
            const bfx8 bv0 = *(const bfx8*)&Vs[(dc * 16 + l15) * 72 + quad * 8];
            const bfx8 bv1 = *(const bfx8*)&Vs[(dc * 16 + l15) * 72 + 32 + quad * 8];
            #pragma unroll
            for (int g = 0; g < 2; ++g) {
                oacc[g][dc] = __builtin_amdgcn_mfma_f32_16x16x32_bf16(ap[g][0], bv0, oacc[g][dc], 0, 0, 0);
                oacc[g][dc] = __builtin_amdgcn_mfma_f32_16x16x32_bf16(ap[g][1], bv1, oacc[g][dc], 0, 0, 0);
            }
        }
    }

    #pragma unroll
    for (int g = 0; g < 2; ++g) {
        float lt = l_run[g];
        lt += __shfl_xor(lt, 16, 64);
        lt += __shfl_xor(lt, 32, 64);
        sums[wave][g * 16 + l15] = lt;
    }
    asm volatile("s_waitcnt lgkmcnt(0)" ::: "memory");

    short* OsW = PsW;
    #pragma unroll
    for (int g = 0; g < 2; ++g) {
        #pragma unroll
        for (int r = 0; r < 4; ++r) {
            int qi = g * 16 + quad * 4 + r;
            float rli = 1.0f / sums[wave][qi];
            #pragma unroll
            for (int dc = 0; dc < 3; ++dc) {
                bf16 hb = __float2bfloat16(oacc[g][dc][r] * rli);
                OsW[qi * 52 + dc * 16 + l15] = *(short*)&hb;
            }
        }
    }
    asm volatile("s_waitcnt lgkmcnt(0)" ::: "memory");
    bf16* aob = AO + ((size_t)b * Nk + n0 + wave * 32) * Ck + hd * Dk;
    #pragma unroll
    for (int i = 0; i < 6; ++i) {
        int c = lane + 64 * i;
        int row = c / 12, col4 = c % 12;
        ushort4 v = *(const ushort4*)&OsW[row * 52 + col4 * 4];
        *(ushort4*)(aob + (size_t)row * Ck + col4 * 4) = v;
    }
}

// ---------------------------------------------------------------------------
// Kernel 3: projection GEMM, pure-MFMA, 2-deep register pipeline.
// ---------------------------------------------------------------------------
__global__ __launch_bounds__(256) void proj_mfma_kernel(
    const bf16* __restrict__ AO, const bf16* __restrict__ Wp,
    const float* __restrict__ bias, float* __restrict__ out)
{
    const int b    = blockIdx.z;
    const int o0   = blockIdx.y * 64;
    const int n0   = blockIdx.x * 128;
    const int wave = threadIdx.x >> 6;
    const int lane = threadIdx.x & 63;
    const int l15  = lane & 15, quad = lane >> 4;

    const bf16* ar = AO + ((size_t)b * Nk + n0 + wave * 32 + l15) * Ck + quad * 8;
    const bf16* wr = Wp + (size_t)(o0 + l15) * Ck + quad * 8;

    f32x4 acc[8];
    #pragma unroll
    for (int i = 0; i < 8; ++i) acc[i] = (f32x4){0.f, 0.f, 0.f, 0.f};

    bfx8 fx[3][2], fw[3][4];
    #define LOAD_STEP(s, bf)                                                  \
        {                                                                     \
            _Pragma("unroll")                                                 \
            for (int i = 0; i < 2; ++i)                                       \
                fx[bf][i] = *(const bfx8*)(ar + (size_t)i * 16 * Ck + (s) * 32); \
            _Pragma("unroll")                                                 \
            for (int j = 0; j < 4; ++j)                                       \
                fw[bf][j] = *(const bfx8*)(wr + (size_t)j * 16 * Ck + (s) * 32); \
        }

    LOAD_STEP(0, 0)
    LOAD_STEP(1, 1)

    #pragma unroll
    for (int s = 0; s < 12; ++s) {
        if (s + 2 < 12) LOAD_STEP(s + 2, (s + 2) % 3)
        const int bf = s % 3;
        #pragma unroll
        for (int j = 0; j < 4; ++j)
            #pragma unroll
            for (int i = 0; i < 2; ++i)
                acc[j * 2 + i] = __builtin_amdgcn_mfma_f32_16x16x32_bf16(
                    fw[bf][j], fx[bf][i], acc[j * 2 + i], 0, 0, 0);
    }
    #undef LOAD_STEP

    #pragma unroll
    for (int j = 0; j < 4; ++j) {
        #pragma unroll
        for (int reg = 0; reg < 4; ++reg) {
            int o  = o0 + j * 16 + quad * 4 + reg;
            float bi = bias[o];
            #pragma unroll
            for (int i = 0; i < 2; ++i) {
                int npos = n0 + wave * 32 + i * 16 + l15;
                out[((size_t)b * Ck + o) * Nk + npos] = acc[j * 2 + i][reg] + bi;
            }
        }
    }
}

extern "C" void kernel_launch(void* const* d_in, const int* in_sizes, int n_in,
                              void* d_out, int out_size, void* d_ws, size_t ws_size,
                              hipStream_t stream)
{
    const float* x      = (const float*)d_in[0];
    const float* w_qkv  = (const float*)d_in[1];
    const float* b_qkv  = (const float*)d_in[2];
    const float* w_proj = (const float*)d_in[3];
    const float* b_proj = (const float*)d_in[4];
    float* out = (float*)d_out;

    const size_t XT_SEG = (size_t)Bk * Nk * Ck;
    const size_t WQ_SEG = (size_t)O3 * Ck;
    const size_t WP_SEG = (size_t)Ck * Ck;
    const size_t QK_SEG = (size_t)Bk * NHk * Nk * Dp;
    const size_t V_SEG  = (size_t)Bk * NHk * Dk * Nk;

    bf16* Xt = (bf16*)d_ws;
    bf16* Wq = Xt + XT_SEG;
    bf16* Wp = Wq + WQ_SEG;
    bf16* Qp = Wp + WP_SEG;
    bf16* Kp = Qp + QK_SEG;
    bf16* Vt = Kp + QK_SEG;
    bf16* AO = Vt + V_SEG;

    padzero_kernel<<<1024, 256, 0, stream>>>(Qp, Kp);
    xpose_kernel<<<dim3(Nk / 32, Ck / 32, Bk), 256, 0, stream>>>(x, Xt);
    wconv_kernel<<<(O3 * Ck + 255) / 256, 256, 0, stream>>>(w_qkv, w_proj, Wq, Wp);
    qkv_mfma_kernel<<<dim3(Nk / 128, O3 / 64, Bk), 256, 0, stream>>>(
        Xt, Wq, b_qkv, Qp, Kp, Vt);
    attn_kernel<<<dim3(Nk / 128, NHk, Bk), 256, 0, stream>>>(Qp, Kp, Vt, AO);
    proj_mfma_kernel<<<dim3(Nk / 128, Ck / 64, Bk), 256, 0, stream>>>(
        AO, Wp, b_proj, out);
}

// Round 8
// 139.551 us; speedup vs baseline: 1.2666x; 1.2666x over previous
//
#include <hip/hip_runtime.h>
#include <hip/hip_bf16.h>

typedef __hip_bfloat16 bf16;
typedef __bf16 bfx8 __attribute__((ext_vector_type(8)));
typedef float f32x4 __attribute__((ext_vector_type(4)));

#define Bk   8
#define Ck   384
#define NHk  8
#define Dk   48
#define Dp   64      // padded head dim for MFMA (pads zeroed by padzero_kernel)
#define Nk   1024
#define O3   1152

// ---------------------------------------------------------------------------
// Swizzled operand layout ("fragment-order"): a matrix [R rows][C cols] is
// stored as [R/16][C/8][16][8]; a wave's MFMA fragment load (row l15, chunk
// s*4+quad) becomes base + lane*8 elems = ONE contiguous 1KB burst instead of
// 16 discrete cachelines 768B apart (R7 post-mortem: TA-divergence bound).
//
// Workspace (bf16 elems):
//   Xs: [b][n/16][48][16][8]     3,145,728   (x^T swizzled)
//   Wq: [o/16][48][16][8]          442,368
//   Wp: [o/16][48][16][8]          147,456
//   Qp: [b][hd][n][Dp]           4,194,304   (scale folded, d>=48 zeroed)
//   Kp: [b][hd][n][Dp]           4,194,304   (d>=48 zeroed)
//   Vt: [b][hd][d][n]            3,145,728
//   AO: [b][n/16][48][16][8]     3,145,728   (attn out, swizzled for proj)
// ---------------------------------------------------------------------------

// Prep 0: zero ONLY the d=48..63 pad lanes of Qp/Kp.
__global__ __launch_bounds__(256) void padzero_kernel(
    bf16* __restrict__ Qp, bf16* __restrict__ Kp)
{
    int idx = blockIdx.x * 256 + threadIdx.x;      // 262144 total
    int buf  = idx >> 17;
    int row  = (idx >> 1) & 65535;
    int half = idx & 1;
    bf16* p = (buf ? Kp : Qp) + (size_t)row * Dp + 48 + half * 8;
    *(int4*)p = (int4){0, 0, 0, 0};
}

// Prep 1: transpose+convert x [b][c][n] fp32 -> Xs swizzled bf16.
__global__ __launch_bounds__(256) void xpose_kernel(
    const float* __restrict__ x, bf16* __restrict__ Xs)
{
    __shared__ bf16 tile[32][33];
    const int b = blockIdx.z, c0 = blockIdx.y * 32, n0 = blockIdx.x * 32;
    const int tn = threadIdx.x & 31, tc = threadIdx.x >> 5;
    const float* xb = x + (size_t)b * Ck * Nk;
    #pragma unroll
    for (int i = 0; i < 4; ++i)
        tile[tc + 8 * i][tn] = __float2bfloat16(xb[(size_t)(c0 + tc + 8 * i) * Nk + n0 + tn]);
    __syncthreads();
    // write swizzle: n_loc = tc+8i, c_loc = tn; value = tile[c_loc][n_loc]
    bf16* base = Xs + ((size_t)b * 64 + (n0 >> 4)) * 48 * 128 + (c0 >> 3) * 128;
    #pragma unroll
    for (int i = 0; i < 4; ++i) {
        int n_loc = tc + 8 * i, c_loc = tn;
        base[(size_t)(n_loc >> 4) * 6144 + (c_loc >> 3) * 128 +
             (n_loc & 15) * 8 + (c_loc & 7)] = tile[c_loc][n_loc];
    }
}

// Prep 2: convert + swizzle both weight matrices.
__global__ __launch_bounds__(256) void wconv_kernel(
    const float* __restrict__ wq, const float* __restrict__ wp,
    bf16* __restrict__ Wq, bf16* __restrict__ Wp)
{
    int i = blockIdx.x * 256 + threadIdx.x;
    if (i < O3 * Ck) {
        int o = i / Ck, c = i - o * Ck;
        Wq[((size_t)(o >> 4) * 48 + (c >> 3)) * 128 + (o & 15) * 8 + (c & 7)] =
            __float2bfloat16(wq[i]);
    }
    if (i < Ck * Ck) {
        int o = i / Ck, c = i - o * Ck;
        Wp[((size_t)(o >> 4) * 48 + (c >> 3)) * 128 + (o & 15) * 8 + (c & 7)] =
            __float2bfloat16(wp[i]);
    }
}

// ---------------------------------------------------------------------------
// Kernel 1: QKV GEMM, pure-MFMA, no LDS; all fragment loads are contiguous
// 1KB wave bursts from the swizzled layouts.
// ---------------------------------------------------------------------------
__global__ __launch_bounds__(256) void qkv_mfma_kernel(
    const bf16* __restrict__ Xs, const bf16* __restrict__ Wq,
    const float* __restrict__ bias,
    bf16* __restrict__ Qp, bf16* __restrict__ Kp, bf16* __restrict__ Vt)
{
    const int b    = blockIdx.z;
    const int by   = blockIdx.y;          // o0 = by*64
    const int bx   = blockIdx.x;          // n0 = bx*128
    const int o0   = by * 64;
    const int n0   = bx * 128;
    const int wave = threadIdx.x >> 6;
    const int lane = threadIdx.x & 63;
    const int l15  = lane & 15, quad = lane >> 4;
    const int t3   = o0 / Ck;

    const bf16* xg[2];
    const bf16* wg[4];
    #pragma unroll
    for (int i = 0; i < 2; ++i)
        xg[i] = Xs + ((size_t)(b * 64 + bx * 8 + wave * 2 + i) * 48) * 128 + lane * 8;
    #pragma unroll
    for (int j = 0; j < 4; ++j)
        wg[j] = Wq + ((size_t)(by * 4 + j) * 48) * 128 + lane * 8;

    f32x4 acc[8];
    #pragma unroll
    for (int i = 0; i < 8; ++i) acc[i] = (f32x4){0.f, 0.f, 0.f, 0.f};

    if (t3 < 2) {
        #pragma unroll
        for (int s = 0; s < 12; ++s) {
            bfx8 fx[2], fw[4];
            #pragma unroll
            for (int i = 0; i < 2; ++i) fx[i] = *(const bfx8*)(xg[i] + s * 512);
            #pragma unroll
            for (int j = 0; j < 4; ++j) fw[j] = *(const bfx8*)(wg[j] + s * 512);
            #pragma unroll
            for (int i = 0; i < 2; ++i)
                #pragma unroll
                for (int j = 0; j < 4; ++j)
                    acc[i * 4 + j] = __builtin_amdgcn_mfma_f32_16x16x32_bf16(
                        fx[i], fw[j], acc[i * 4 + j], 0, 0, 0);
        }
        const float qscale = 0.144337567297406441f;  // 48^-0.5
        #pragma unroll
        for (int j = 0; j < 4; ++j) {
            int o  = o0 + j * 16 + l15;
            float bi = bias[o];
            int r  = o - t3 * Ck;
            int hd = r / Dk, d = r - hd * Dk;
            bf16* dst = (t3 == 0 ? Qp : Kp) + ((size_t)(b * NHk + hd) * Nk) * Dp + d;
            #pragma unroll
            for (int i = 0; i < 2; ++i) {
                #pragma unroll
                for (int reg = 0; reg < 4; ++reg) {
                    int npos = n0 + wave * 32 + i * 16 + quad * 4 + reg;
                    float v = acc[i * 4 + j][reg] + bi;
                    if (t3 == 0) v *= qscale;
                    dst[(size_t)npos * Dp] = __float2bfloat16(v);
                }
            }
        }
    } else {
        #pragma unroll
        for (int s = 0; s < 12; ++s) {
            bfx8 fx[2], fw[4];
            #pragma unroll
            for (int i = 0; i < 2; ++i) fx[i] = *(const bfx8*)(xg[i] + s * 512);
            #pragma unroll
            for (int j = 0; j < 4; ++j) fw[j] = *(const bfx8*)(wg[j] + s * 512);
            #pragma unroll
            for (int j = 0; j < 4; ++j)
                #pragma unroll
                for (int i = 0; i < 2; ++i)
                    acc[j * 2 + i] = __builtin_amdgcn_mfma_f32_16x16x32_bf16(
                        fw[j], fx[i], acc[j * 2 + i], 0, 0, 0);
        }
        #pragma unroll
        for (int j = 0; j < 4; ++j) {
            #pragma unroll
            for (int reg = 0; reg < 4; ++reg) {
                int o  = o0 + j * 16 + quad * 4 + reg;
                float bi = bias[o];
                int r  = o - 2 * Ck;
                int hd = r / Dk, d = r - hd * Dk;
                #pragma unroll
                for (int i = 0; i < 2; ++i) {
                    int npos = n0 + wave * 32 + i * 16 + l15;
                    Vt[((size_t)(b * NHk + hd) * Dk + d) * Nk + npos] =
                        __float2bfloat16(acc[j * 2 + i][reg] + bi);
                }
            }
        }
    }
}

// ---------------------------------------------------------------------------
// Kernel 2: MFMA attention, no-max softmax, S^T trick. Epilogue now writes
// AO in swizzled fragment-order (vectorized int4 stores).
// ---------------------------------------------------------------------------
__global__ __launch_bounds__(256) void attn_kernel(
    const bf16* __restrict__ Qp, const bf16* __restrict__ Kp,
    const bf16* __restrict__ Vt, bf16* __restrict__ AO)
{
    __shared__ __align__(16) short Ks[64 * 72];
    __shared__ __align__(16) short Vs[48 * 72];
    __shared__ __align__(16) short Ps[4 * 32 * 72];
    __shared__ float sums[4][32];

    const int bx   = blockIdx.x;
    const int n0   = bx * 128;
    const int hd   = blockIdx.y;
    const int b    = blockIdx.z;
    const int t    = threadIdx.x;
    const int wave = t >> 6;
    const int lane = t & 63;
    const int l15  = lane & 15;
    const int quad = lane >> 4;

    const bf16* qb = Qp + (size_t)(b * NHk + hd) * Nk * Dp;
    const bf16* kb = Kp + (size_t)(b * NHk + hd) * Nk * Dp;
    const bf16* vb = Vt + (size_t)(b * NHk + hd) * Dk * Nk;

    bfx8 bq[2][2];
    #pragma unroll
    for (int g = 0; g < 2; ++g) {
        const bf16* qr = qb + (size_t)(n0 + wave * 32 + g * 16 + l15) * Dp;
        bq[g][0] = *(const bfx8*)(qr + quad * 8);
        bq[g][1] = *(const bfx8*)(qr + 32 + quad * 8);
    }

    float l_run[2] = {0.f, 0.f};
    f32x4 oacc[2][3];
    #pragma unroll
    for (int g = 0; g < 2; ++g)
        #pragma unroll
        for (int dc = 0; dc < 3; ++dc) oacc[g][dc] = (f32x4){0.f, 0.f, 0.f, 0.f};

    short* PsW = Ps + wave * 32 * 72;

    for (int k0 = 0; k0 < Nk; k0 += 64) {
        __syncthreads();
        {
            const bf16* src = kb + (size_t)k0 * Dp;
            #pragma unroll
            for (int i = 0; i < 2; ++i) {
                int c = t + 256 * i;
                int row = c >> 3, part = c & 7;
                *(bfx8*)&Ks[row * 72 + part * 8] = *(const bfx8*)(src + c * 8);
            }
            for (int c = t; c < 384; c += 256) {
                int d = c >> 3, part = c & 7;
                *(bfx8*)&Vs[d * 72 + part * 8] =
                    *(const bfx8*)(vb + (size_t)d * Nk + k0 + part * 8);
            }
        }
        __syncthreads();

        f32x4 sf[4][2];
        #pragma unroll
        for (int s = 0; s < 4; ++s) {
            const bfx8 kf0 = *(const bfx8*)&Ks[(s * 16 + l15) * 72 + quad * 8];
            const bfx8 kf1 = *(const bfx8*)&Ks[(s * 16 + l15) * 72 + 32 + quad * 8];
            #pragma unroll
            for (int g = 0; g < 2; ++g) {
                f32x4 z = (f32x4){0.f, 0.f, 0.f, 0.f};
                z = __builtin_amdgcn_mfma_f32_16x16x32_bf16(kf0, bq[g][0], z, 0, 0, 0);
                z = __builtin_amdgcn_mfma_f32_16x16x32_bf16(kf1, bq[g][1], z, 0, 0, 0);
                sf[s][g] = z;
            }
        }

        #pragma unroll
        for (int g = 0; g < 2; ++g) {
            float lsum = 0.f;
            #pragma unroll
            for (int s = 0; s < 4; ++s) {
                ushort4 pk;
                float e0 = __expf(sf[s][g][0]);
                float e1 = __expf(sf[s][g][1]);
                float e2 = __expf(sf[s][g][2]);
                float e3 = __expf(sf[s][g][3]);
                lsum += (e0 + e1) + (e2 + e3);
                bf16 h0 = __float2bfloat16(e0), h1 = __float2bfloat16(e1);
                bf16 h2 = __float2bfloat16(e2), h3 = __float2bfloat16(e3);
                pk.x = *(unsigned short*)&h0; pk.y = *(unsigned short*)&h1;
                pk.z = *(unsigned short*)&h2; pk.w = *(unsigned short*)&h3;
                *(ushort4*)&PsW[(g * 16 + l15) * 72 + s * 16 + quad * 4] = pk;
            }
            l_run[g] += lsum;
        }

        asm volatile("s_waitcnt lgkmcnt(0)" ::: "memory");

        bfx8 ap[2][2];
        #pragma unroll
        for (int g = 0; g < 2; ++g) {
            ap[g][0] = *(const bfx8*)&PsW[(g * 16 + l15) * 72 + quad * 8];
            ap[g][1] = *(const bfx8*)&PsW[(g * 16 + l15) * 72 + 32 + quad * 8];
        }
        #pragma unroll
        for (int dc = 0; dc < 3; ++dc) {
            const bfx8 bv0 = *(const bfx8*)&Vs[(dc * 16 + l15) * 72 + quad * 8];
            const bfx8 bv1 = *(const bfx8*)&Vs[(dc * 16 + l15) * 72 + 32 + quad * 8];
            #pragma unroll
            for (int g = 0; g < 2; ++g) {
                oacc[g][dc] = __builtin_amdgcn_mfma_f32_16x16x32_bf16(ap[g][0], bv0, oacc[g][dc], 0, 0, 0);
                oacc[g][dc] = __builtin_amdgcn_mfma_f32_16x16x32_bf16(ap[g][1], bv1, oacc[g][dc], 0, 0, 0);
            }
        }
    }

    #pragma unroll
    for (int g = 0; g < 2; ++g) {
        float lt = l_run[g];
        lt += __shfl_xor(lt, 16, 64);
        lt += __shfl_xor(lt, 32, 64);
        sums[wave][g * 16 + l15] = lt;
    }
    asm volatile("s_waitcnt lgkmcnt(0)" ::: "memory");

    // normalize into per-wave LDS (stride 64 shorts, 16B-aligned rows)
    short* OsW = PsW;   // 32*64 = 2048 shorts < 2304 region
    #pragma unroll
    for (int g = 0; g < 2; ++g) {
        #pragma unroll
        for (int r = 0; r < 4; ++r) {
            int qi = g * 16 + quad * 4 + r;
            float rli = 1.0f / sums[wave][qi];
            #pragma unroll
            for (int dcc = 0; dcc < 3; ++dcc) {
                bf16 hb = __float2bfloat16(oacc[g][dcc][r] * rli);
                OsW[qi * 64 + dcc * 16 + l15] = *(short*)&hb;
            }
        }
    }
    asm volatile("s_waitcnt lgkmcnt(0)" ::: "memory");

    // swizzled AO store: group G = bx*8 + wave*2 + g, chunks hd*6 + (0..5)
    // unit u = dc*16 + row -> dst offset u*16B (contiguous)
    #pragma unroll
    for (int g = 0; g < 2; ++g) {
        bf16* aob = AO + (((size_t)b * 64 + bx * 8 + wave * 2 + g) * 48 + hd * 6) * 128;
        int u = lane;
        int4 v = *(const int4*)&OsW[(g * 16 + (u & 15)) * 64 + (u >> 4) * 8];
        *(int4*)(aob + u * 8) = v;
        if (lane < 32) {
            int u2 = 64 + lane;
            int4 v2 = *(const int4*)&OsW[(g * 16 + (u2 & 15)) * 64 + (u2 >> 4) * 8];
            *(int4*)(aob + u2 * 8) = v2;
        }
    }
}

// ---------------------------------------------------------------------------
// Kernel 3: projection GEMM, pure-MFMA, swizzled operands (contiguous bursts).
// ---------------------------------------------------------------------------
__global__ __launch_bounds__(256) void proj_mfma_kernel(
    const bf16* __restrict__ AO, const bf16* __restrict__ Wp,
    const float* __restrict__ bias, float* __restrict__ out)
{
    const int b    = blockIdx.z;
    const int by   = blockIdx.y;
    const int bx   = blockIdx.x;
    const int o0   = by * 64;
    const int n0   = bx * 128;
    const int wave = threadIdx.x >> 6;
    const int lane = threadIdx.x & 63;
    const int l15  = lane & 15, quad = lane >> 4;

    const bf16* ag[2];
    const bf16* wg[4];
    #pragma unroll
    for (int i = 0; i < 2; ++i)
        ag[i] = AO + ((size_t)(b * 64 + bx * 8 + wave * 2 + i) * 48) * 128 + lane * 8;
    #pragma unroll
    for (int j = 0; j < 4; ++j)
        wg[j] = Wp + ((size_t)(by * 4 + j) * 48) * 128 + lane * 8;

    f32x4 acc[8];
    #pragma unroll
    for (int i = 0; i < 8; ++i) acc[i] = (f32x4){0.f, 0.f, 0.f, 0.f};

    #pragma unroll
    for (int s = 0; s < 12; ++s) {
        bfx8 fx[2], fw[4];
        #pragma unroll
        for (int i = 0; i < 2; ++i) fx[i] = *(const bfx8*)(ag[i] + s * 512);
        #pragma unroll
        for (int j = 0; j < 4; ++j) fw[j] = *(const bfx8*)(wg[j] + s * 512);
        #pragma unroll
        for (int j = 0; j < 4; ++j)
            #pragma unroll
            for (int i = 0; i < 2; ++i)
                acc[j * 2 + i] = __builtin_amdgcn_mfma_f32_16x16x32_bf16(
                    fw[j], fx[i], acc[j * 2 + i], 0, 0, 0);
    }

    #pragma unroll
    for (int j = 0; j < 4; ++j) {
        #pragma unroll
        for (int reg = 0; reg < 4; ++reg) {
            int o  = o0 + j * 16 + quad * 4 + reg;
            float bi = bias[o];
            #pragma unroll
            for (int i = 0; i < 2; ++i) {
                int npos = n0 + wave * 32 + i * 16 + l15;
                out[((size_t)b * Ck + o) * Nk + npos] = acc[j * 2 + i][reg] + bi;
            }
        }
    }
}

extern "C" void kernel_launch(void* const* d_in, const int* in_sizes, int n_in,
                              void* d_out, int out_size, void* d_ws, size_t ws_size,
                              hipStream_t stream)
{
    const float* x      = (const float*)d_in[0];
    const float* w_qkv  = (const float*)d_in[1];
    const float* b_qkv  = (const float*)d_in[2];
    const float* w_proj = (const float*)d_in[3];
    const float* b_proj = (const float*)d_in[4];
    float* out = (float*)d_out;

    const size_t XT_SEG = (size_t)Bk * Nk * Ck;
    const size_t WQ_SEG = (size_t)O3 * Ck;
    const size_t WP_SEG = (size_t)Ck * Ck;
    const size_t QK_SEG = (size_t)Bk * NHk * Nk * Dp;
    const size_t V_SEG  = (size_t)Bk * NHk * Dk * Nk;

    bf16* Xs = (bf16*)d_ws;
    bf16* Wq = Xs + XT_SEG;
    bf16* Wp = Wq + WQ_SEG;
    bf16* Qp = Wp + WP_SEG;
    bf16* Kp = Qp + QK_SEG;
    bf16* Vt = Kp + QK_SEG;
    bf16* AO = Vt + V_SEG;

    padzero_kernel<<<1024, 256, 0, stream>>>(Qp, Kp);
    xpose_kernel<<<dim3(Nk / 32, Ck / 32, Bk), 256, 0, stream>>>(x, Xs);
    wconv_kernel<<<(O3 * Ck + 255) / 256, 256, 0, stream>>>(w_qkv, w_proj, Wq, Wp);
    qkv_mfma_kernel<<<dim3(Nk / 128, O3 / 64, Bk), 256, 0, stream>>>(
        Xs, Wq, b_qkv, Qp, Kp, Vt);
    attn_kernel<<<dim3(Nk / 128, NHk, Bk), 256, 0, stream>>>(Qp, Kp, Vt, AO);
    proj_mfma_kernel<<<dim3(Nk / 128, Ck / 64, Bk), 256, 0, stream>>>(
        AO, Wp, b_proj, out);
}